// Round 10
// baseline (295.901 us; speedup 1.0000x reference)
//
#include <hip/hip_runtime.h>

typedef float f32x4 __attribute__((ext_vector_type(4)));
typedef short s16x8 __attribute__((ext_vector_type(8)));
typedef unsigned int u32;

#define HDIM 160
#define NT 10          // n-tiles of 16 (160 hidden outputs)
#define KS 5           // k-steps of 32 (K=160)
#define CH 20          // 16B chunks per bf16 row (320 B)
#define STAGE_I 10     // 32 rows * 20 chunks / 64 lanes
#define BUFSH (32 * HDIM)  // 5120 shorts = 10240 B per row buffer

__device__ __forceinline__ unsigned short f2bf(float f) {
    union { float f; unsigned u; } v; v.f = f;
    unsigned u = v.u;
    return (unsigned short)((u + 0x7FFFu + ((u >> 16) & 1u)) >> 16);
}

__device__ __forceinline__ float u2f(u32 u) {
    union { u32 u; float f; } v; v.u = u; return v.f;
}
__device__ __forceinline__ u32 f2u(float f) {
    union { float f; u32 u; } v; v.f = f; return v.u;
}

// x f32 -> bf16 (RNE) into ws; zeroes the miss counter.
__global__ void prep_x_kernel(const float* __restrict__ x,
                              unsigned short* __restrict__ xbf,
                              int* __restrict__ counter, int n4) {
    int idx = blockIdx.x * blockDim.x + threadIdx.x;
    if (idx == 0) *counter = 0;
    if (idx < n4) {
        f32x4 w = ((const f32x4*)x)[idx];
        union { unsigned short h[4]; unsigned long long u; } p;
        p.h[0] = f2bf(w.x); p.h[1] = f2bf(w.y);
        p.h[2] = f2bf(w.z); p.h[3] = f2bf(w.w);
        ((unsigned long long*)xbf)[idx] = p.u;
    }
}

__global__ void zero_kernel(int* __restrict__ counter) {
    if (threadIdx.x == 0) *counter = 0;
}

// TRUE depth-2 pipeline: edge indices staged via global_load_lds (4B) into a
// 3-slot LDS ring, read back with ds_read (lgkmcnt) -- vmcnt FIFO carries ONLY
// LDS-DMA, 11 ops/iter, one manual vmcnt(11)/iter, zero forced drains.
// 3 row buffers (mod-3) + 3 idx slots = 31488 B -> 4 blocks/CU at (64,1).
__global__ __launch_bounds__(64, 1) void gae_main_bf16(
    const unsigned short* __restrict__ xbf,
    const int* __restrict__ pos,
    const int* __restrict__ neg,
    const float* __restrict__ W1,
    const float* __restrict__ b1,
    const float* __restrict__ W2,
    const float* __restrict__ b2,
    int* __restrict__ counter,
    int Ep, int En) {
    __shared__ unsigned short rowbuf[3][BUFSH];  // 3 x 10240 B
    __shared__ int idxlds[3][64];                // 3 x 256 B

    const int E = Ep + En;
    const int lane = threadIdx.x;   // 64-thread block = 1 wave
    const int c = lane & 15;        // edge-in-tile (A row); output col (B/C)
    const int q = lane >> 4;        // k-quad (A/B); row-quad (C)
    const int D = gridDim.x;        // total waves
    const int numIter = (E + 15) >> 4;

    // ---- all 50 B-fragments (tile-invariant) -> registers, from f32 W1 ----
    s16x8 bfr[KS][NT];
#pragma unroll
    for (int s = 0; s < KS; s++) {
#pragma unroll
        for (int n = 0; n < NT; n++) {
            const float* wp = W1 + (size_t)(n * 16 + c) * HDIM + 32 * s + 8 * q;
            f32x4 w0 = *(const f32x4*)wp;
            f32x4 w1v = *(const f32x4*)(wp + 4);
#pragma unroll
            for (int e = 0; e < 4; e++) {
                bfr[s][n][e]     = (short)f2bf(w0[e]);
                bfr[s][n][e + 4] = (short)f2bf(w1v[e]);
            }
        }
    }

    float b1r[NT], w2r[NT];
#pragma unroll
    for (int n = 0; n < NT; n++) {
        b1r[n] = b1[n * 16 + c];
        w2r[n] = W2[n * 16 + c];
    }
    const float b2v = b2[0];

    // ---- hoisted per-(tt,lane) staging constants (tile-invariant) ----
    // row r = f/20, stored chunk cp = f%20, source chunk d = (cp - r) mod 20.
    int rArr4[STAGE_I];  // r * 4  (byte offset into idx slot)
    int dOff[STAGE_I];   // d * 16 (byte offset into source row)
#pragma unroll
    for (int tt = 0; tt < STAGE_I; tt++) {
        int f = tt * 64 + lane;
        int r = (f * 3277) >> 16;   // f / 20, exact for f < 640
        int cp = f - CH * r;
        int d = cp - r;
        d += (d < 0) ? CH : 0;
        d += (d < 0) ? CH : 0;
        rArr4[tt] = r * 4;
        dOff[tt] = d * 16;
    }

    // Stage 32 edge indices of tile T into idx slot (1 vmem op).
    // dest = slot base + lane*4; lanes 0-15: i, 16-31: j, 32-63: dup (ignored).
#define STAGE_IDX(T, SLOT)                                               \
    {                                                                    \
        int e = ((T) << 4) + (lane & 15);                                \
        e = (e < E) ? e : (E - 1);                                       \
        const int* bi = (e < Ep) ? (pos + e) : (neg + (e - Ep));         \
        const int* bj = (e < Ep) ? (pos + Ep + e) : (neg + En + (e - Ep)); \
        const int* srcI = ((lane >> 4) & 1) ? bj : bi;                   \
        __builtin_amdgcn_global_load_lds(                                \
            (const __attribute__((address_space(1))) void*)srcI,         \
            (__attribute__((address_space(3))) void*)(&idxlds[SLOT][0]), \
            4, 0, 0);                                                    \
    }

    // Stage 32 bf16 rows x 320 B into row buffer (10 vmem ops); indices come
    // from the idx slot via ds_read (no vmcnt involvement).
#define STAGE_ROWS(RSLOT, ISLOT)                                         \
    {                                                                    \
        const char* ib = (const char*)&idxlds[ISLOT][0];                 \
        unsigned short* rb = rowbuf[RSLOT];                              \
        _Pragma("unroll")                                                \
        for (int tt = 0; tt < STAGE_I; tt++) {                           \
            int rowIdx = *(const int*)(ib + rArr4[tt]);                  \
            const char* src =                                            \
                (const char*)(xbf + (size_t)rowIdx * HDIM) + dOff[tt];   \
            __builtin_amdgcn_global_load_lds(                            \
                (const __attribute__((address_space(1))) void*)src,      \
                (__attribute__((address_space(3))) void*)(rb + tt * 512),\
                16, 0, 0);                                               \
        }                                                                \
    }

    int cnt = 0;
    int t = blockIdx.x;

    // ---- prologue: order matters for vmcnt(11) at iter0:
    // rows(t)10, idx(t+2D)1  [oldest 11]  |  rows(t+D)10, idx(t+3D)1
    STAGE_IDX(t, 0);
    STAGE_IDX(t + D, 1);
    __builtin_amdgcn_s_waitcnt(0x0F70);  // vmcnt(0): idx(t), idx(t+D) landed
    STAGE_ROWS(0, 0);                     // rows(t)
    STAGE_IDX(t + 2 * D, 0);              // idx slot 0 reused for t+2D
    STAGE_ROWS(1, 1);                     // rows(t+D)
    STAGE_IDX(t + 3 * D, 1);              // idx slot 1 for t+3D

    int p = 0;
    for (; t < numIter; t += D) {
        const int e0 = t << 4;
        int p2 = p + 2; p2 -= (p2 >= 3) ? 3 : 0;

        __builtin_amdgcn_sched_barrier(0);
        __builtin_amdgcn_s_waitcnt(0x0F7B);  // vmcnt(11): rows(t)+idx(t+2D)
        __builtin_amdgcn_sched_barrier(0);   // landed; t+D's 11 stay in flight

        STAGE_ROWS(p2, p);                   // rows(t+2D), idx from slot p
        STAGE_IDX(t + 4 * D, p2);            // idx(t+4D) -> slot p2
        __builtin_amdgcn_sched_barrier(0);

        // ---- compute tile t from rowbuf[p] (LDS + regs only) ----
        const unsigned short* buf = rowbuf[p];
        f32x4 acc[NT];
#pragma unroll
        for (int n = 0; n < NT; n++) acc[n] = (f32x4)(0.0f);

#pragma unroll
        for (int s = 0; s < KS; s++) {
            int pi = 4 * s + q + c;          // rotated chunk pos, row c
            pi -= (pi >= CH) ? CH : 0;
            int pj = 4 * s + q + 16 + c;     // rotated chunk pos, row 16+c
            pj -= (pj >= CH) ? CH : 0;
            pj -= (pj >= CH) ? CH : 0;
            union { s16x8 v; u32 w[4]; } U, V, A;
            U.v = *(const s16x8*)(buf + c * HDIM + pi * 8);
            V.v = *(const s16x8*)(buf + (16 + c) * HDIM + pj * 8);
#pragma unroll
            for (int h = 0; h < 4; h++) {
                u32 uw = U.w[h], vw = V.w[h];
                float ul = u2f(uw << 16), uh = u2f(uw & 0xffff0000u);
                float vl = u2f(vw << 16), vh = u2f(vw & 0xffff0000u);
                float pl = fmaxf(ul * vl, 0.0f);
                float ph = fmaxf(uh * vh, 0.0f);
                // pack hi16(ph):hi16(pl) in one v_perm (truncation; margin huge)
                A.w[h] = __builtin_amdgcn_perm(f2u(ph), f2u(pl), 0x07060302u);
            }
#pragma unroll
            for (int n = 0; n < NT; n++) {
                acc[n] = __builtin_amdgcn_mfma_f32_16x16x32_bf16(A.v, bfr[s][n], acc[n], 0, 0, 0);
            }
        }

        // ---- epilogue: logit = W2 . relu(acc + b1) + b2, count misses ----
        float sArr[4] = {0.0f, 0.0f, 0.0f, 0.0f};
#pragma unroll
        for (int n = 0; n < NT; n++) {
#pragma unroll
            for (int r = 0; r < 4; r++) {
                sArr[r] += fmaxf(acc[n][r] + b1r[n], 0.0f) * w2r[n];
            }
        }
#pragma unroll
        for (int r = 0; r < 4; r++) {
            float sv = sArr[r];
            sv += __shfl_xor(sv, 1);
            sv += __shfl_xor(sv, 2);
            sv += __shfl_xor(sv, 4);
            sv += __shfl_xor(sv, 8);
            if (c == 0) {
                int ge = e0 + q * 4 + r;  // D row = edge-in-tile
                if (ge < E) {
                    float logit = sv + b2v;
                    bool miss = (ge < Ep) ? (logit <= 0.5f) : (logit > 0.5f);
                    cnt += miss ? 1 : 0;
                }
            }
        }

        p = p + 1; p -= (p >= 3) ? 3 : 0;
    }
    // Drain in-flight LDS-DMA before block exit (LDS may be reassigned).
    __builtin_amdgcn_s_waitcnt(0x0F70);  // vmcnt(0)

    cnt += __shfl_xor(cnt, 1);
    cnt += __shfl_xor(cnt, 2);
    cnt += __shfl_xor(cnt, 4);
    cnt += __shfl_xor(cnt, 8);
    cnt += __shfl_xor(cnt, 16);
    cnt += __shfl_xor(cnt, 32);
    if (lane == 0) atomicAdd(counter, cnt);
#undef STAGE_IDX
#undef STAGE_ROWS
}

// ---- fallback (ws too small for bf16 x): round-8 f32 dbuf kernel ----
#define STAGE_F 20
#define BUFNF (32 * HDIM)
__global__ __launch_bounds__(64, 1) void gae_main_f32(
    const float* __restrict__ x,
    const int* __restrict__ pos,
    const int* __restrict__ neg,
    const float* __restrict__ W1,
    const float* __restrict__ b1,
    const float* __restrict__ W2,
    const float* __restrict__ b2,
    int* __restrict__ counter,
    int Ep, int En) {
    __shared__ float rowbuf[2][BUFNF];
    const int E = Ep + En;
    const int lane = threadIdx.x;
    const int c = lane & 15;
    const int q = lane >> 4;
    const int D = gridDim.x;
    const int numIter = (E + 15) >> 4;

    s16x8 bfr[KS][NT];
#pragma unroll
    for (int s = 0; s < KS; s++) {
#pragma unroll
        for (int n = 0; n < NT; n++) {
            const float* wp = W1 + (size_t)(n * 16 + c) * HDIM + 32 * s + 8 * q;
            f32x4 w0 = *(const f32x4*)wp;
            f32x4 w1v = *(const f32x4*)(wp + 4);
#pragma unroll
            for (int e = 0; e < 4; e++) {
                bfr[s][n][e]     = (short)f2bf(w0[e]);
                bfr[s][n][e + 4] = (short)f2bf(w1v[e]);
            }
        }
    }
    float b1r[NT], w2r[NT];
#pragma unroll
    for (int n = 0; n < NT; n++) { b1r[n] = b1[n*16+c]; w2r[n] = W2[n*16+c]; }
    const float b2v = b2[0];

#define LOAD_IDXF(T, I, J) { int e = ((T) << 4) + c; e = (e < E) ? e : (E-1); \
    const int* bi = (e < Ep) ? (pos + e) : (neg + (e - Ep)); \
    const int* bj = (e < Ep) ? (pos + Ep + e) : (neg + En + (e - Ep)); \
    (I) = *bi; (J) = *bj; }
#define STAGEF(IA, JA, BUF) { _Pragma("unroll") \
    for (int tt = 0; tt < STAGE_F; tt++) { \
        int f = tt * 64 + lane; \
        int r = (f * 1639) >> 16; \
        int cp = f - 40 * r; \
        int cs = cp - r; cs = (cs < 0) ? cs + 40 : cs; \
        int ri = __shfl((IA), r); \
        int rj = __shfl((JA), r); \
        int rowIdx = (r < 16) ? ri : rj; \
        const float* src = x + (size_t)rowIdx * HDIM + cs * 4; \
        __builtin_amdgcn_global_load_lds( \
            (const __attribute__((address_space(1))) void*)src, \
            (__attribute__((address_space(3))) void*)((BUF) + tt * 256), \
            16, 0, 0); } }

    int cnt = 0;
    int t = blockIdx.x;
    int iC, jC, iN, jN;
    if (t < numIter) {
        LOAD_IDXF(t, iC, jC);
        STAGEF(iC, jC, rowbuf[0]);
        LOAD_IDXF(t + D, iN, jN);
        __builtin_amdgcn_s_waitcnt(0x0F70);
    }
    int p = 0;
    for (; t < numIter; t += D) {
        const int e0 = t << 4;
        STAGEF(iN, jN, rowbuf[p ^ 1]);
        int i2, j2;
        LOAD_IDXF(t + 2 * D, i2, j2);
        __builtin_amdgcn_sched_barrier(0);
        const float* buf = rowbuf[p];
        f32x4 acc[NT];
#pragma unroll
        for (int n = 0; n < NT; n++) acc[n] = (f32x4)(0.0f);
#pragma unroll
        for (int s = 0; s < KS; s++) {
            const int c8 = 8 * s + 2 * q;
            int p0 = c8 + c;       p0 -= (p0 >= 40) ? 40 : 0;
            int p1 = c8 + 1 + c;   p1 -= (p1 >= 40) ? 40 : 0;
            int pj0 = c8 + 16 + c; pj0 -= (pj0 >= 40) ? 40 : 0;
            int pj1 = c8 + 17 + c; pj1 -= (pj1 >= 40) ? 40 : 0;
            f32x4 u0 = *(const f32x4*)(buf + c * HDIM + p0 * 4);
            f32x4 u1 = *(const f32x4*)(buf + c * HDIM + p1 * 4);
            f32x4 v0 = *(const f32x4*)(buf + (16 + c) * HDIM + pj0 * 4);
            f32x4 v1 = *(const f32x4*)(buf + (16 + c) * HDIM + pj1 * 4);
            s16x8 af;
#pragma unroll
            for (int e = 0; e < 4; e++) {
                af[e]     = (short)f2bf(fmaxf(u0[e] * v0[e], 0.0f));
                af[e + 4] = (short)f2bf(fmaxf(u1[e] * v1[e], 0.0f));
            }
#pragma unroll
            for (int n = 0; n < NT; n++)
                acc[n] = __builtin_amdgcn_mfma_f32_16x16x32_bf16(af, bfr[s][n], acc[n], 0, 0, 0);
        }
        float sArr[4] = {0.0f, 0.0f, 0.0f, 0.0f};
#pragma unroll
        for (int n = 0; n < NT; n++)
#pragma unroll
            for (int r = 0; r < 4; r++)
                sArr[r] += fmaxf(acc[n][r] + b1r[n], 0.0f) * w2r[n];
#pragma unroll
        for (int r = 0; r < 4; r++) {
            float sv = sArr[r];
            sv += __shfl_xor(sv, 1);
            sv += __shfl_xor(sv, 2);
            sv += __shfl_xor(sv, 4);
            sv += __shfl_xor(sv, 8);
            if (c == 0) {
                int ge = e0 + q * 4 + r;
                if (ge < E) {
                    float logit = sv + b2v;
                    bool miss = (ge < Ep) ? (logit <= 0.5f) : (logit > 0.5f);
                    cnt += miss ? 1 : 0;
                }
            }
        }
        iN = i2; jN = j2;
        __builtin_amdgcn_s_waitcnt(0x0F70);
        __builtin_amdgcn_sched_barrier(0);
        p ^= 1;
    }
    cnt += __shfl_xor(cnt, 1);
    cnt += __shfl_xor(cnt, 2);
    cnt += __shfl_xor(cnt, 4);
    cnt += __shfl_xor(cnt, 8);
    cnt += __shfl_xor(cnt, 16);
    cnt += __shfl_xor(cnt, 32);
    if (lane == 0) atomicAdd(counter, cnt);
#undef LOAD_IDXF
#undef STAGEF
}

__global__ void finalize_kernel(const int* __restrict__ counter,
                                float* __restrict__ out) {
    if (blockIdx.x == 0 && threadIdx.x == 0) {
        out[0] = 100.0f * (float)(*counter) / 512.0f;
    }
}

extern "C" void kernel_launch(void* const* d_in, const int* in_sizes, int n_in,
                              void* d_out, int out_size, void* d_ws, size_t ws_size,
                              hipStream_t stream) {
    const float* x = (const float*)d_in[0];
    const int* pos = (const int*)d_in[1];
    const int* neg = (const int*)d_in[2];
    // d_in[3] = batch: irrelevant — mean over all 512 segment-sums == total/512
    const float* W1 = (const float*)d_in[4];
    const float* b1 = (const float*)d_in[5];
    const float* W2 = (const float*)d_in[6];
    const float* b2 = (const float*)d_in[7];

    const int Ep = in_sizes[1] / 2;
    const int En = in_sizes[2] / 2;
    const int xn = in_sizes[0];  // 100000*160

    int* counter = (int*)d_ws;
    unsigned short* xbf = (unsigned short*)((char*)d_ws + 256);
    const size_t wsNeeded = 256 + (size_t)xn * 2;

    if (ws_size >= wsNeeded) {
        const int n4 = xn / 4;
        prep_x_kernel<<<(n4 + 255) / 256, 256, 0, stream>>>(x, xbf, counter, n4);
        gae_main_bf16<<<1024, 64, 0, stream>>>(xbf, pos, neg, W1, b1, W2, b2,
                                               counter, Ep, En);
    } else {
        zero_kernel<<<1, 64, 0, stream>>>(counter);
        gae_main_f32<<<1024, 64, 0, stream>>>(x, pos, neg, W1, b1, W2, b2,
                                              counter, Ep, En);
    }
    finalize_kernel<<<1, 64, 0, stream>>>(counter, (float*)d_out);
}

// Round 11
// 219.635 us; speedup vs baseline: 1.3472x; 1.3472x over previous
//
#include <hip/hip_runtime.h>

typedef float f32x4 __attribute__((ext_vector_type(4)));
typedef float f32x2 __attribute__((ext_vector_type(2)));
typedef short s16x8 __attribute__((ext_vector_type(8)));
typedef unsigned int u32;
typedef unsigned int u32x2 __attribute__((ext_vector_type(2)));

#define HDIM 160
#define NT 10          // n-tiles of 16 (160 hidden outputs)
#define KS 5           // k-steps of 32 (K=160)
#define CHF 10         // 16B chunks per fp8 row (160 B)
#define STAGE_I 5      // 32 rows * 10 chunks / 64 lanes
#define BUFB (32 * HDIM)  // 5120 B per fp8 row buffer

__device__ __forceinline__ unsigned short f2bf(float f) {
    union { float f; unsigned u; } v; v.f = f;
    unsigned u = v.u;
    return (unsigned short)((u + 0x7FFFu + ((u >> 16) & 1u)) >> 16);
}

// x f32 -> fp8 e4m3 (sat) into ws; zeroes the miss counter. 8 elems/thread.
__global__ void prep_x_fp8(const float* __restrict__ x,
                           u32* __restrict__ xf8,
                           int* __restrict__ counter, int n8) {
    int idx = blockIdx.x * blockDim.x + threadIdx.x;
    if (idx == 0) *counter = 0;
    if (idx < n8) {
        f32x4 a = ((const f32x4*)x)[idx * 2];
        f32x4 b = ((const f32x4*)x)[idx * 2 + 1];
        u32 lo = __builtin_amdgcn_cvt_pk_fp8_f32(a.x, a.y, 0u, false);
        lo = __builtin_amdgcn_cvt_pk_fp8_f32(a.z, a.w, lo, true);
        u32 hi = __builtin_amdgcn_cvt_pk_fp8_f32(b.x, b.y, 0u, false);
        hi = __builtin_amdgcn_cvt_pk_fp8_f32(b.z, b.w, hi, true);
        u32x2 o; o.x = lo; o.y = hi;
        ((u32x2*)xf8)[idx] = o;
    }
}

__global__ void zero_kernel(int* __restrict__ counter) {
    if (threadIdx.x == 0) *counter = 0;
}

// fp8 path: 80 lines/tile staged (6 vmem ops/iter incl idx), W1 fp8 in 100
// VGPRs, mfma fp8_fp8. (64,2): <=256 regs -> 2 waves/SIMD; 8x 16.1KB blocks/CU.
__global__ __launch_bounds__(64, 2) void gae_main_fp8(
    const u32* __restrict__ xf8,
    const int* __restrict__ pos,
    const int* __restrict__ neg,
    const float* __restrict__ W1,
    const float* __restrict__ b1,
    const float* __restrict__ W2,
    const float* __restrict__ b2,
    int* __restrict__ counter,
    int Ep, int En) {
    __shared__ char rowbuf[3][BUFB];   // 3 x 5120 B
    __shared__ int idxlds[3][64];      // 3 x 256 B

    const int E = Ep + En;
    const int lane = threadIdx.x;   // 64-thread block = 1 wave
    const int c = lane & 15;        // edge-in-tile (A row); output col (B/C)
    const int q = lane >> 4;        // k-quad (A/B); row-quad (C)
    const int D = gridDim.x;
    const int numIter = (E + 15) >> 4;

    // ---- 50 B-fragments (tile-invariant) -> fp8 in 100 VGPRs ----
    u32 bfr_lo[KS][NT], bfr_hi[KS][NT];
#pragma unroll
    for (int s = 0; s < KS; s++) {
#pragma unroll
        for (int n = 0; n < NT; n++) {
            const float* wp = W1 + (size_t)(n * 16 + c) * HDIM + 32 * s + 8 * q;
            f32x4 w0 = *(const f32x4*)wp;
            f32x4 w1v = *(const f32x4*)(wp + 4);
            u32 lo = __builtin_amdgcn_cvt_pk_fp8_f32(w0.x, w0.y, 0u, false);
            lo = __builtin_amdgcn_cvt_pk_fp8_f32(w0.z, w0.w, lo, true);
            u32 hi = __builtin_amdgcn_cvt_pk_fp8_f32(w1v.x, w1v.y, 0u, false);
            hi = __builtin_amdgcn_cvt_pk_fp8_f32(w1v.z, w1v.w, hi, true);
            bfr_lo[s][n] = lo; bfr_hi[s][n] = hi;
        }
    }

    float b1r[NT], w2r[NT];
#pragma unroll
    for (int n = 0; n < NT; n++) {
        b1r[n] = b1[n * 16 + c];
        w2r[n] = W2[n * 16 + c];
    }
    const float b2v = b2[0];

    // ---- hoisted staging constants: f = tt*64+lane, r = f/10, cp = f%10,
    // source chunk d = (cp - r) mod 10; stored pos = (d + r) mod 10 = cp.
    int rArr4[STAGE_I];  // r * 4 (offset into idx slot)
    int dOff[STAGE_I];   // d * 16 (byte offset into source row)
#pragma unroll
    for (int tt = 0; tt < STAGE_I; tt++) {
        int f = tt * 64 + lane;
        int r = (f * 6554) >> 16;        // f / 10
        int cp = f - 10 * r;
        int r10 = r - 10 * ((r * 6554) >> 16);  // r % 10
        int d = cp - r10;
        d += (d < 0) ? CHF : 0;
        rArr4[tt] = r * 4;
        dOff[tt] = d * 16;
    }

#define STAGE_IDX(T, SLOT)                                               \
    {                                                                    \
        int e = ((T) << 4) + (lane & 15);                                \
        e = (e < E) ? e : (E - 1);                                       \
        const int* bi = (e < Ep) ? (pos + e) : (neg + (e - Ep));         \
        const int* bj = (e < Ep) ? (pos + Ep + e) : (neg + En + (e - Ep)); \
        const int* srcI = ((lane >> 4) & 1) ? bj : bi;                   \
        __builtin_amdgcn_global_load_lds(                                \
            (const __attribute__((address_space(1))) void*)srcI,         \
            (__attribute__((address_space(3))) void*)(&idxlds[SLOT][0]), \
            4, 0, 0);                                                    \
    }

#define STAGE_ROWS(RSLOT, ISLOT)                                         \
    {                                                                    \
        const char* ib = (const char*)&idxlds[ISLOT][0];                 \
        char* rb = rowbuf[RSLOT];                                        \
        _Pragma("unroll")                                                \
        for (int tt = 0; tt < STAGE_I; tt++) {                           \
            int rowIdx = *(const int*)(ib + rArr4[tt]);                  \
            const char* src =                                            \
                (const char*)(xf8) + (size_t)rowIdx * HDIM + dOff[tt];   \
            __builtin_amdgcn_global_load_lds(                            \
                (const __attribute__((address_space(1))) void*)src,      \
                (__attribute__((address_space(3))) void*)(rb + tt * 1024),\
                16, 0, 0);                                               \
        }                                                                \
    }

    int cnt = 0;
    int t = blockIdx.x;

    // ---- prologue: FIFO = [rows(t)5, idx(t+2D)1 | rows(t+D)5, idx(t+3D)1]
    STAGE_IDX(t, 0);
    STAGE_IDX(t + D, 1);
    __builtin_amdgcn_s_waitcnt(0x0F70);  // vmcnt(0)
    STAGE_ROWS(0, 0);
    STAGE_IDX(t + 2 * D, 0);
    STAGE_ROWS(1, 1);
    STAGE_IDX(t + 3 * D, 1);

    int p = 0;
    for (; t < numIter; t += D) {
        const int e0 = t << 4;
        int p2 = p + 2; p2 -= (p2 >= 3) ? 3 : 0;

        __builtin_amdgcn_sched_barrier(0);
        __builtin_amdgcn_s_waitcnt(0x0F76);  // vmcnt(6): rows(t)+idx(t+2D) in
        __builtin_amdgcn_sched_barrier(0);

        STAGE_ROWS(p2, p);                   // rows(t+2D)
        STAGE_IDX(t + 4 * D, p2);
        __builtin_amdgcn_sched_barrier(0);

        // ---- compute tile t from rowbuf[p] ----
        const char* buf = rowbuf[p];
        f32x4 acc[NT];
#pragma unroll
        for (int n = 0; n < NT; n++) acc[n] = (f32x4)(0.0f);

#pragma unroll
        for (int s = 0; s < KS; s++) {
            int d = 2 * s + (q >> 1);        // source chunk of this 8B half
            int off8 = 8 * (q & 1);
            int pi = d + c;                  // stored pos, i-row c
            pi -= (pi >= CHF) ? CHF : 0;
            pi -= (pi >= CHF) ? CHF : 0;
            int pj = d + 6 + c;              // stored pos, j-row 16+c
            pj -= (pj >= CHF) ? CHF : 0;
            pj -= (pj >= CHF) ? CHF : 0;
            pj -= (pj >= CHF) ? CHF : 0;
            u32x2 iw = *(const u32x2*)(buf + c * HDIM + pi * 16 + off8);
            u32x2 jw = *(const u32x2*)(buf + (16 + c) * HDIM + pj * 16 + off8);
            f32x2 i01 = __builtin_amdgcn_cvt_pk_f32_fp8(iw.x, false);
            f32x2 i23 = __builtin_amdgcn_cvt_pk_f32_fp8(iw.x, true);
            f32x2 i45 = __builtin_amdgcn_cvt_pk_f32_fp8(iw.y, false);
            f32x2 i67 = __builtin_amdgcn_cvt_pk_f32_fp8(iw.y, true);
            f32x2 j01 = __builtin_amdgcn_cvt_pk_f32_fp8(jw.x, false);
            f32x2 j23 = __builtin_amdgcn_cvt_pk_f32_fp8(jw.x, true);
            f32x2 j45 = __builtin_amdgcn_cvt_pk_f32_fp8(jw.y, false);
            f32x2 j67 = __builtin_amdgcn_cvt_pk_f32_fp8(jw.y, true);
            float p0 = fmaxf(i01.x * j01.x, 0.0f);
            float p1 = fmaxf(i01.y * j01.y, 0.0f);
            float p2f = fmaxf(i23.x * j23.x, 0.0f);
            float p3 = fmaxf(i23.y * j23.y, 0.0f);
            float p4 = fmaxf(i45.x * j45.x, 0.0f);
            float p5 = fmaxf(i45.y * j45.y, 0.0f);
            float p6 = fmaxf(i67.x * j67.x, 0.0f);
            float p7 = fmaxf(i67.y * j67.y, 0.0f);
            u32 alo = __builtin_amdgcn_cvt_pk_fp8_f32(p0, p1, 0u, false);
            alo = __builtin_amdgcn_cvt_pk_fp8_f32(p2f, p3, alo, true);
            u32 ahi = __builtin_amdgcn_cvt_pk_fp8_f32(p4, p5, 0u, false);
            ahi = __builtin_amdgcn_cvt_pk_fp8_f32(p6, p7, ahi, true);
            long afr = (long)(((unsigned long long)ahi << 32) |
                              (unsigned long long)alo);
#pragma unroll
            for (int n = 0; n < NT; n++) {
                long bf8 = (long)(((unsigned long long)bfr_hi[s][n] << 32) |
                                  (unsigned long long)bfr_lo[s][n]);
                acc[n] = __builtin_amdgcn_mfma_f32_16x16x32_fp8_fp8(
                    afr, bf8, acc[n], 0, 0, 0);
            }
        }

        // ---- epilogue: logit = W2 . relu(acc + b1) + b2, count misses ----
        float sArr[4] = {0.0f, 0.0f, 0.0f, 0.0f};
#pragma unroll
        for (int n = 0; n < NT; n++) {
#pragma unroll
            for (int r = 0; r < 4; r++) {
                sArr[r] += fmaxf(acc[n][r] + b1r[n], 0.0f) * w2r[n];
            }
        }
#pragma unroll
        for (int r = 0; r < 4; r++) {
            float sv = sArr[r];
            sv += __shfl_xor(sv, 1);
            sv += __shfl_xor(sv, 2);
            sv += __shfl_xor(sv, 4);
            sv += __shfl_xor(sv, 8);
            if (c == 0) {
                int ge = e0 + q * 4 + r;
                if (ge < E) {
                    float logit = sv + b2v;
                    bool miss = (ge < Ep) ? (logit <= 0.5f) : (logit > 0.5f);
                    cnt += miss ? 1 : 0;
                }
            }
        }

        p = p + 1; p -= (p >= 3) ? 3 : 0;
    }
    __builtin_amdgcn_s_waitcnt(0x0F70);  // drain DMA before LDS reassignment

    cnt += __shfl_xor(cnt, 1);
    cnt += __shfl_xor(cnt, 2);
    cnt += __shfl_xor(cnt, 4);
    cnt += __shfl_xor(cnt, 8);
    cnt += __shfl_xor(cnt, 16);
    cnt += __shfl_xor(cnt, 32);
    if (lane == 0) atomicAdd(counter, cnt);
#undef STAGE_IDX
#undef STAGE_ROWS
}

// ---- fallback (ws too small): round-8 f32 dbuf kernel (proven 237us) ----
#define STAGE_F 20
#define BUFNF (32 * HDIM)
__global__ __launch_bounds__(64, 1) void gae_main_f32(
    const float* __restrict__ x,
    const int* __restrict__ pos,
    const int* __restrict__ neg,
    const float* __restrict__ W1,
    const float* __restrict__ b1,
    const float* __restrict__ W2,
    const float* __restrict__ b2,
    int* __restrict__ counter,
    int Ep, int En) {
    __shared__ float rowbuf[2][BUFNF];
    const int E = Ep + En;
    const int lane = threadIdx.x;
    const int c = lane & 15;
    const int q = lane >> 4;
    const int D = gridDim.x;
    const int numIter = (E + 15) >> 4;

    s16x8 bfr[KS][NT];
#pragma unroll
    for (int s = 0; s < KS; s++) {
#pragma unroll
        for (int n = 0; n < NT; n++) {
            const float* wp = W1 + (size_t)(n * 16 + c) * HDIM + 32 * s + 8 * q;
            f32x4 w0 = *(const f32x4*)wp;
            f32x4 w1v = *(const f32x4*)(wp + 4);
#pragma unroll
            for (int e = 0; e < 4; e++) {
                bfr[s][n][e]     = (short)f2bf(w0[e]);
                bfr[s][n][e + 4] = (short)f2bf(w1v[e]);
            }
        }
    }
    float b1r[NT], w2r[NT];
#pragma unroll
    for (int n = 0; n < NT; n++) { b1r[n] = b1[n*16+c]; w2r[n] = W2[n*16+c]; }
    const float b2v = b2[0];

#define LOAD_IDXF(T, I, J) { int e = ((T) << 4) + c; e = (e < E) ? e : (E-1); \
    const int* bi = (e < Ep) ? (pos + e) : (neg + (e - Ep)); \
    const int* bj = (e < Ep) ? (pos + Ep + e) : (neg + En + (e - Ep)); \
    (I) = *bi; (J) = *bj; }
#define STAGEF(IA, JA, BUF) { _Pragma("unroll") \
    for (int tt = 0; tt < STAGE_F; tt++) { \
        int f = tt * 64 + lane; \
        int r = (f * 1639) >> 16; \
        int cp = f - 40 * r; \
        int cs = cp - r; cs = (cs < 0) ? cs + 40 : cs; \
        int ri = __shfl((IA), r); \
        int rj = __shfl((JA), r); \
        int rowIdx = (r < 16) ? ri : rj; \
        const float* src = x + (size_t)rowIdx * HDIM + cs * 4; \
        __builtin_amdgcn_global_load_lds( \
            (const __attribute__((address_space(1))) void*)src, \
            (__attribute__((address_space(3))) void*)((BUF) + tt * 256), \
            16, 0, 0); } }

    int cnt = 0;
    int t = blockIdx.x;
    int iC, jC, iN, jN;
    if (t < numIter) {
        LOAD_IDXF(t, iC, jC);
        STAGEF(iC, jC, rowbuf[0]);
        LOAD_IDXF(t + D, iN, jN);
        __builtin_amdgcn_s_waitcnt(0x0F70);
    }
    int p = 0;
    for (; t < numIter; t += D) {
        const int e0 = t << 4;
        STAGEF(iN, jN, rowbuf[p ^ 1]);
        int i2, j2;
        LOAD_IDXF(t + 2 * D, i2, j2);
        __builtin_amdgcn_sched_barrier(0);
        const float* buf = rowbuf[p];
        f32x4 acc[NT];
#pragma unroll
        for (int n = 0; n < NT; n++) acc[n] = (f32x4)(0.0f);
#pragma unroll
        for (int s = 0; s < KS; s++) {
            const int c8 = 8 * s + 2 * q;
            int p0 = c8 + c;       p0 -= (p0 >= 40) ? 40 : 0;
            int p1 = c8 + 1 + c;   p1 -= (p1 >= 40) ? 40 : 0;
            int pj0 = c8 + 16 + c; pj0 -= (pj0 >= 40) ? 40 : 0;
            int pj1 = c8 + 17 + c; pj1 -= (pj1 >= 40) ? 40 : 0;
            f32x4 u0 = *(const f32x4*)(buf + c * HDIM + p0 * 4);
            f32x4 u1 = *(const f32x4*)(buf + c * HDIM + p1 * 4);
            f32x4 v0 = *(const f32x4*)(buf + (16 + c) * HDIM + pj0 * 4);
            f32x4 v1 = *(const f32x4*)(buf + (16 + c) * HDIM + pj1 * 4);
            s16x8 af;
#pragma unroll
            for (int e = 0; e < 4; e++) {
                af[e]     = (short)f2bf(fmaxf(u0[e] * v0[e], 0.0f));
                af[e + 4] = (short)f2bf(fmaxf(u1[e] * v1[e], 0.0f));
            }
#pragma unroll
            for (int n = 0; n < NT; n++)
                acc[n] = __builtin_amdgcn_mfma_f32_16x16x32_bf16(af, bfr[s][n], acc[n], 0, 0, 0);
        }
        float sArr[4] = {0.0f, 0.0f, 0.0f, 0.0f};
#pragma unroll
        for (int n = 0; n < NT; n++)
#pragma unroll
            for (int r = 0; r < 4; r++)
                sArr[r] += fmaxf(acc[n][r] + b1r[n], 0.0f) * w2r[n];
#pragma unroll
        for (int r = 0; r < 4; r++) {
            float sv = sArr[r];
            sv += __shfl_xor(sv, 1);
            sv += __shfl_xor(sv, 2);
            sv += __shfl_xor(sv, 4);
            sv += __shfl_xor(sv, 8);
            if (c == 0) {
                int ge = e0 + q * 4 + r;
                if (ge < E) {
                    float logit = sv + b2v;
                    bool miss = (ge < Ep) ? (logit <= 0.5f) : (logit > 0.5f);
                    cnt += miss ? 1 : 0;
                }
            }
        }
        iN = i2; jN = j2;
        __builtin_amdgcn_s_waitcnt(0x0F70);
        __builtin_amdgcn_sched_barrier(0);
        p ^= 1;
    }
    cnt += __shfl_xor(cnt, 1);
    cnt += __shfl_xor(cnt, 2);
    cnt += __shfl_xor(cnt, 4);
    cnt += __shfl_xor(cnt, 8);
    cnt += __shfl_xor(cnt, 16);
    cnt += __shfl_xor(cnt, 32);
    if (lane == 0) atomicAdd(counter, cnt);
#undef LOAD_IDXF
#undef STAGEF
}

__global__ void finalize_kernel(const int* __restrict__ counter,
                                float* __restrict__ out) {
    if (blockIdx.x == 0 && threadIdx.x == 0) {
        out[0] = 100.0f * (float)(*counter) / 512.0f;
    }
}

extern "C" void kernel_launch(void* const* d_in, const int* in_sizes, int n_in,
                              void* d_out, int out_size, void* d_ws, size_t ws_size,
                              hipStream_t stream) {
    const float* x = (const float*)d_in[0];
    const int* pos = (const int*)d_in[1];
    const int* neg = (const int*)d_in[2];
    // d_in[3] = batch: irrelevant — mean over all 512 segment-sums == total/512
    const float* W1 = (const float*)d_in[4];
    const float* b1 = (const float*)d_in[5];
    const float* W2 = (const float*)d_in[6];
    const float* b2 = (const float*)d_in[7];

    const int Ep = in_sizes[1] / 2;
    const int En = in_sizes[2] / 2;
    const int xn = in_sizes[0];  // 100000*160

    int* counter = (int*)d_ws;
    u32* xf8 = (u32*)((char*)d_ws + 256);
    const size_t wsNeeded = 256 + (size_t)xn;  // 1 B/elem

    if (ws_size >= wsNeeded) {
        const int n8 = xn / 8;
        prep_x_fp8<<<(n8 + 255) / 256, 256, 0, stream>>>(x, xf8, counter, n8);
        // 2048 blocks x 64 thr: 8 blocks/CU (LDS 16.1 KB, <=256 regs)
        gae_main_fp8<<<2048, 64, 0, stream>>>(xf8, pos, neg, W1, b1, W2, b2,
                                              counter, Ep, En);
    } else {
        zero_kernel<<<1, 64, 0, stream>>>(counter);
        gae_main_f32<<<1024, 64, 0, stream>>>(x, pos, neg, W1, b1, W2, b2,
                                              counter, Ep, En);
    }
    finalize_kernel<<<1, 64, 0, stream>>>(counter, (float*)d_out);
}